// Round 1
// baseline (230.746 us; speedup 1.0000x reference)
//
#include <hip/hip_runtime.h>

// Problem constants (match reference file)
constexpr int B = 32;
constexpr int L = 512;
constexpr int D = 384;
constexpr int T = 4096;
constexpr int VPR = D / 4;                 // float4 per output row = 96
constexpr int OUT0 = B * T * D;            // elements in first output
constexpr int RPB = 16;                    // output rows per block
constexpr int BLOCKS_PER_BATCH = T / RPB;  // 256
constexpr int NBLK = B * BLOCKS_PER_BATCH; // 8192
constexpr int BS = 256;                    // threads per block
constexpr int PASSES = RPB * VPR / BS;     // 6

typedef float f32x4 __attribute__((ext_vector_type(4)));

// Kernel 1: per-batch inclusive cumsum of durations, write exp_dur (f32),
// and SCATTER the inverse map: srcmap[b][j] = global source row feeding
// output slot j, or -1 if that slot is zeros (masked token / past total).
// Token t covers output slots [cum[t]-d, cum[t]) — this is exactly
// searchsorted(cum, j, side="right") inverted, 0-duration tokens excluded.
__global__ __launch_bounds__(L) void map_k(const int* __restrict__ dur,
                                           const int* __restrict__ mask,
                                           int* __restrict__ srcmap,
                                           float* __restrict__ expd) {
    const int b = blockIdx.x;
    const int t = threadIdx.x;
    __shared__ int s[L];
    int d = dur[b * L + t];
    // EXPAND_SCALE == 1.0 -> round(1.0 * d) == d
    expd[b * L + t] = (float)d;
    s[t] = d;
    __syncthreads();
    #pragma unroll
    for (int off = 1; off < L; off <<= 1) {
        int v = (t >= off) ? s[t - off] : 0;
        __syncthreads();
        s[t] += v;
        __syncthreads();
    }
    const int end = s[t];                  // inclusive cumsum

    // init map to -1: 8 slots/thread (T = 8*L), vectorized int4 stores
    int4* m4 = (int4*)(srcmap + b * T);
    m4[t * 2 + 0] = make_int4(-1, -1, -1, -1);
    m4[t * 2 + 1] = make_int4(-1, -1, -1, -1);
    // __syncthreads() lowers to s_waitcnt vmcnt(0) + s_barrier: the -1
    // stores are committed (same CU -> same L2 path) before any scatter
    // store below can race them.
    __syncthreads();

    // scatter this token's span (<= 7 slots; max total 512*7 = 3584 < T)
    if (d > 0 && !mask[b * L + t]) {
        const int src = b * L + t;         // absolute source row
        int* m = srcmap + b * T;
        for (int k = end - d; k < end; ++k) m[k] = src;
    }
}

// Kernel 2: pure streaming gather-copy. No LDS, no barriers, no searches.
// Each block owns RPB=16 consecutive output rows of one batch: reads one
// 64 B srcmap line (L1-resident across all 6 passes) and streams 24 KB of
// fully contiguous nontemporal float4 stores (201 MB total, zero reuse —
// keep it out of L2 so seq stays cached).
__global__ __launch_bounds__(BS) void copy_k(const f32x4* __restrict__ seq,
                                             const int* __restrict__ srcmap,
                                             f32x4* __restrict__ out) {
    const int blk  = blockIdx.x;
    const int b    = blk >> 8;             // / BLOCKS_PER_BATCH
    const int row0 = (blk & 255) * RPB;    // first output slot of this block
    const int tid  = threadIdx.x;

    const int* __restrict__ m = srcmap + b * T + row0;   // 16 ints = 1 line
    f32x4* obase = out + (size_t)(b * T + row0) * VPR;

    #pragma unroll
    for (int p = 0; p < PASSES; ++p) {
        const int idx = p * BS + tid;      // 0..1535
        const int r   = idx / VPR;         // constant div -> magic mul
        const int col = idx - r * VPR;
        const int s   = m[r];              // 4 B, same cache line block-wide
        f32x4 v = {0.f, 0.f, 0.f, 0.f};
        if (s >= 0) v = seq[(size_t)s * VPR + col];
        __builtin_nontemporal_store(v, obase + idx);
    }
}

extern "C" void kernel_launch(void* const* d_in, const int* in_sizes, int n_in,
                              void* d_out, int out_size, void* d_ws, size_t ws_size,
                              hipStream_t stream) {
    const float* seq  = (const float*)d_in[0];
    const int*   dur  = (const int*)d_in[1];
    const int*   mask = (const int*)d_in[2];
    // d_in[3] = max_length scalar (4096 == T)

    float* out      = (float*)d_out;
    float* expd_out = out + OUT0;

    int* srcmap = (int*)d_ws;              // B*T*4 = 512 KB scratch

    map_k<<<B, L, 0, stream>>>(dur, mask, srcmap, expd_out);
    copy_k<<<NBLK, BS, 0, stream>>>((const f32x4*)seq, srcmap, (f32x4*)out);
}

// Round 2
// 220.317 us; speedup vs baseline: 1.0473x; 1.0473x over previous
//
#include <hip/hip_runtime.h>

// Problem constants (match reference file)
constexpr int B = 32;
constexpr int L = 512;
constexpr int D = 384;
constexpr int T = 4096;
constexpr int VPR = D / 4;                 // float4 per output row = 96
constexpr int OUT0 = B * T * D;            // elements in first output
constexpr int RPB = 16;                    // output rows per block
constexpr int BLOCKS_PER_BATCH = T / RPB;  // 256
constexpr int NBLK = B * BLOCKS_PER_BATCH; // 8192
constexpr int BS = 256;                    // threads per block
constexpr int PASSES = RPB * VPR / BS;     // 6

typedef float f32x4 __attribute__((ext_vector_type(4)));

// Kernel 1: per-batch inclusive cumsum of durations, write exp_dur (f32),
// and SCATTER the inverse map: srcmap[b][j] = global source row feeding
// output slot j, or -1 if that slot is zeros (masked token / past total).
__global__ __launch_bounds__(L) void map_k(const int* __restrict__ dur,
                                           const int* __restrict__ mask,
                                           int* __restrict__ srcmap,
                                           float* __restrict__ expd) {
    const int b = blockIdx.x;
    const int t = threadIdx.x;
    __shared__ int s[L];
    int d = dur[b * L + t];
    // EXPAND_SCALE == 1.0 -> round(1.0 * d) == d
    expd[b * L + t] = (float)d;
    s[t] = d;
    __syncthreads();
    #pragma unroll
    for (int off = 1; off < L; off <<= 1) {
        int v = (t >= off) ? s[t - off] : 0;
        __syncthreads();
        s[t] += v;
        __syncthreads();
    }
    const int end = s[t];                  // inclusive cumsum

    // init map to -1: 8 slots/thread (T = 8*L), vectorized int4 stores
    int4* m4 = (int4*)(srcmap + b * T);
    m4[t * 2 + 0] = make_int4(-1, -1, -1, -1);
    m4[t * 2 + 1] = make_int4(-1, -1, -1, -1);
    // __syncthreads() lowers to s_waitcnt vmcnt(0) + s_barrier: the -1
    // stores are committed before any scatter store below can race them
    // (same block -> same CU -> same L2 path).
    __syncthreads();

    // scatter this token's span (<= 7 slots; max total 512*7 = 3584 < T)
    if (d > 0 && !mask[b * L + t]) {
        const int src = b * L + t;         // absolute source row
        int* m = srcmap + b * T;
        for (int k = end - d; k < end; ++k) m[k] = src;
    }
}

// Kernel 2: pure streaming gather-copy, restructured for memory-level
// parallelism: phase 1 loads all 6 srcmap entries, phase 2 issues all 6
// gather dwordx4 loads UNCONDITIONALLY (clamped index, branchless), phase 3
// zero-selects and stores. Every wave has 6 outstanding VMEM loads before
// the first dependent store wait -> latency-bound becomes BW-bound.
__global__ __launch_bounds__(BS) void copy_k(const f32x4* __restrict__ seq,
                                             const int* __restrict__ srcmap,
                                             f32x4* __restrict__ out) {
    const int blk  = blockIdx.x;
    const int b    = blk >> 8;             // / BLOCKS_PER_BATCH
    const int row0 = (blk & 255) * RPB;    // first output slot of this block
    const int tid  = threadIdx.x;

    const int* __restrict__ m = srcmap + b * T + row0;   // 16 ints = 1 line
    f32x4* obase = out + (size_t)(b * T + row0) * VPR;

    int   s[PASSES];
    f32x4 v[PASSES];

    // phase 1: map entries (L1-resident line, broadcast within wave)
    #pragma unroll
    for (int p = 0; p < PASSES; ++p) {
        const int idx = p * BS + tid;      // 0..1535
        const int r   = idx / VPR;         // constant div -> magic mul
        s[p] = m[r];
    }

    // phase 2: 6 independent gather loads, no control flow
    #pragma unroll
    for (int p = 0; p < PASSES; ++p) {
        const int idx = p * BS + tid;
        const int r   = idx / VPR;
        const int col = idx - r * VPR;
        const int sr  = s[p] < 0 ? 0 : s[p];          // clamp (cndmask)
        v[p] = seq[(size_t)sr * VPR + col];
    }

    // phase 3: zero-select + contiguous stores (full 64B lines per wave)
    #pragma unroll
    for (int p = 0; p < PASSES; ++p) {
        const f32x4 z = {0.f, 0.f, 0.f, 0.f};
        obase[p * BS + tid] = (s[p] < 0) ? z : v[p];
    }
}

extern "C" void kernel_launch(void* const* d_in, const int* in_sizes, int n_in,
                              void* d_out, int out_size, void* d_ws, size_t ws_size,
                              hipStream_t stream) {
    const float* seq  = (const float*)d_in[0];
    const int*   dur  = (const int*)d_in[1];
    const int*   mask = (const int*)d_in[2];
    // d_in[3] = max_length scalar (4096 == T)

    float* out      = (float*)d_out;
    float* expd_out = out + OUT0;

    int* srcmap = (int*)d_ws;              // B*T*4 = 512 KB scratch

    map_k<<<B, L, 0, stream>>>(dur, mask, srcmap, expd_out);
    copy_k<<<NBLK, BS, 0, stream>>>((const f32x4*)seq, srcmap, (f32x4*)out);
}